// Round 6
// baseline (299.639 us; speedup 1.0000x reference)
//
#include <hip/hip_runtime.h>
#include <hip/hip_bf16.h>
#include <math.h>

#define Bz 2
#define Tz 2048
#define Cz 1024
#define Hz 16
#define HKVz 4
#define Dz 64
#define GATE_CHz 32
#define QKV_N 1536          // H*D + 2*HKV*D
#define ROWS (Bz*Tz)        // 4096

typedef __attribute__((ext_vector_type(8))) short bf16x8;
typedef __attribute__((ext_vector_type(4))) float f32x4;

static __device__ __forceinline__ f32x4 MFMA16(bf16x8 a, bf16x8 b, f32x4 c) {
    return __builtin_amdgcn_mfma_f32_16x16x32_bf16(a, b, c, 0, 0, 0);
}
static __device__ __forceinline__ unsigned short f2bf(float f) {
    unsigned int u = __float_as_uint(f);
    unsigned int r = (u + 0x7FFFu + ((u >> 16) & 1u)) >> 16;   // RNE
    return (unsigned short)r;
}
static __device__ __forceinline__ float bf2f(unsigned short u) {
    return __uint_as_float(((unsigned int)u) << 16);
}

// ---------------------------------------------------------------------------
// fp32 -> bf16 conversion (8 elems/thread), n % 8 == 0
// ---------------------------------------------------------------------------
__global__ __launch_bounds__(256) void cvt_bf16(const float* __restrict__ s,
                                                unsigned short* __restrict__ d, int n)
{
    int i = (blockIdx.x * 256 + threadIdx.x) * 8;
    if (i >= n) return;
    float4 a = *(const float4*)(s + i);
    float4 b = *(const float4*)(s + i + 4);
    union { unsigned short u[8]; uint4 v; } o;
    o.u[0] = f2bf(a.x); o.u[1] = f2bf(a.y); o.u[2] = f2bf(a.z); o.u[3] = f2bf(a.w);
    o.u[4] = f2bf(b.x); o.u[5] = f2bf(b.y); o.u[6] = f2bf(b.z); o.u[7] = f2bf(b.w);
    *(uint4*)(d + i) = o.v;
}

// ---------------------------------------------------------------------------
// bf16 MFMA GEMM (NT): C[m][n] = sum_k A[m][k]*B[n][k].
// Tile 64(M) x 128(N), BK=64. 4 waves (2x2: 32M x 64N each). 24KB LDS,
// T2 XOR swizzle, register prefetch, bijective XCD-swizzled 1-D grid,
// LDS-staged coalesced C-write. OB=1: bf16 out, OB=0: fp32 out.
// M fixed = 4096 (gy=64); gx = N/128 passed in; grid = gx*64, %8==0.
// ---------------------------------------------------------------------------
template<int OB>
__global__ __launch_bounds__(256) void gemm_bf16(const unsigned short* __restrict__ A,
                                                 const unsigned short* __restrict__ Bw,
                                                 void* __restrict__ Cv, int K, int ldc,
                                                 int gx)
{
    __shared__ unsigned short smem[64 * 64 + 128 * 64];   // A 8KB | B 16KB (24KB)
    char* ab = (char*)smem;
    char* bb = (char*)(smem + 64 * 64);

    const int tid = threadIdx.x;
    const int wid = tid >> 6, l = tid & 63;
    const int wr = wid >> 1, wc = wid & 1;
    const int lg = l >> 4, lr = l & 15;
    const int swz = (lr & 7) << 4;

    // XCD-aware bijective swizzle (grid % 8 == 0)
    const int nwg = gx * 64;
    const int cpx = nwg >> 3;
    const int sbid = (blockIdx.x & 7) * cpx + (blockIdx.x >> 3);
    const int bx = sbid % gx;           // N-tile (fastest: blocks sharing A-panel adjacent)
    const int by = sbid / gx;           // M-tile

    // staging maps
    const int arow = tid >> 2, aoff = (tid & 3) * 32;     // A: 32B per thread
    const int brow = tid >> 1, boff = (tid & 1) * 64;     // B: 64B per thread
    const unsigned short* Ag = A  + (size_t)(by * 64 + arow) * K + aoff / 2;
    const unsigned short* Bg = Bw + (size_t)(bx * 128 + brow) * K + boff / 2;
    const int awb = arow * 128 + aoff, asw = (arow & 7) << 4;
    const int bwb = brow * 128 + boff, bsw = (brow & 7) << 4;

    uint4 ra[2], rb[4];
    #pragma unroll
    for (int j = 0; j < 2; ++j) ra[j] = *(const uint4*)(Ag + j * 8);
    #pragma unroll
    for (int j = 0; j < 4; ++j) rb[j] = *(const uint4*)(Bg + j * 8);

    f32x4 acc[2][4];
    #pragma unroll
    for (int m = 0; m < 2; ++m)
        #pragma unroll
        for (int n = 0; n < 4; ++n)
            acc[m][n] = (f32x4){0.f, 0.f, 0.f, 0.f};

    const int nk = K / 64;
    for (int ki = 0; ki < nk; ++ki) {
        #pragma unroll
        for (int j = 0; j < 2; ++j)
            *(uint4*)(ab + ((awb + j * 16) ^ asw)) = ra[j];
        #pragma unroll
        for (int j = 0; j < 4; ++j)
            *(uint4*)(bb + ((bwb + j * 16) ^ bsw)) = rb[j];
        __syncthreads();
        if (ki + 1 < nk) {
            const int k0 = (ki + 1) * 64;
            #pragma unroll
            for (int j = 0; j < 2; ++j) ra[j] = *(const uint4*)(Ag + k0 + j * 8);
            #pragma unroll
            for (int j = 0; j < 4; ++j) rb[j] = *(const uint4*)(Bg + k0 + j * 8);
        }
        #pragma unroll
        for (int kk = 0; kk < 2; ++kk) {
            bf16x8 av[2], bv[4];
            #pragma unroll
            for (int m = 0; m < 2; ++m)
                av[m] = *(const bf16x8*)(ab + (((wr * 32 + m * 16 + lr) * 128 + kk * 64 + lg * 16) ^ swz));
            #pragma unroll
            for (int n = 0; n < 4; ++n)
                bv[n] = *(const bf16x8*)(bb + (((wc * 64 + n * 16 + lr) * 128 + kk * 64 + lg * 16) ^ swz));
            #pragma unroll
            for (int m = 0; m < 2; ++m)
                #pragma unroll
                for (int n = 0; n < 4; ++n)
                    acc[m][n] = MFMA16(av[m], bv[n], acc[m][n]);
        }
        __syncthreads();
    }

    // ---- LDS-staged coalesced C-write ----
    if (OB) {
        // bf16: full 64x128 tile = 16KB in smem
        unsigned short* cs = smem;
        #pragma unroll
        for (int m = 0; m < 2; ++m)
            #pragma unroll
            for (int n = 0; n < 4; ++n)
                #pragma unroll
                for (int r = 0; r < 4; ++r)
                    cs[(wr * 32 + m * 16 + lg * 4 + r) * 128 + wc * 64 + n * 16 + lr]
                        = f2bf(acc[m][n][r]);
        __syncthreads();
        unsigned short* C = (unsigned short*)Cv;
        #pragma unroll
        for (int it = 0; it < 4; ++it) {
            const int idx = it * 256 + tid;           // 0..1023 uint4 chunks
            const int row = idx >> 4, c16 = idx & 15; // 16 uint4 per 256B row
            *(uint4*)&C[(size_t)(by * 64 + row) * ldc + bx * 128 + c16 * 8]
                = *(const uint4*)&cs[row * 128 + c16 * 8];
        }
    } else {
        // fp32: two 32-row half-tiles of 16KB
        float* cf = (float*)smem;
        float* C = (float*)Cv;
        #pragma unroll
        for (int p = 0; p < 2; ++p) {
            if (wr == p) {
                #pragma unroll
                for (int m = 0; m < 2; ++m)
                    #pragma unroll
                    for (int n = 0; n < 4; ++n)
                        #pragma unroll
                        for (int r = 0; r < 4; ++r)
                            cf[(m * 16 + lg * 4 + r) * 128 + wc * 64 + n * 16 + lr]
                                = acc[m][n][r];
            }
            __syncthreads();
            #pragma unroll
            for (int it = 0; it < 4; ++it) {
                const int idx = it * 256 + tid;           // 0..1023 uint4 chunks
                const int row = idx >> 5, c32 = idx & 31; // 32 uint4 per 512B row
                *(uint4*)&C[(size_t)(by * 64 + p * 32 + row) * ldc + bx * 128 + c32 * 4]
                    = *(const uint4*)&cf[row * 128 + c32 * 4];
            }
            __syncthreads();
        }
    }
}

// ---------------------------------------------------------------------------
// Epilogue on bf16 qkv: one wave per (row, head-slot).
// slots 0..15 q, 16..19 k (rope+rms); 20..23 v (gate*ve add).
// ---------------------------------------------------------------------------
__global__ __launch_bounds__(256) void epilogue_kernel(unsigned short* __restrict__ qkv,
                                                       const float* __restrict__ x,
                                                       const float* __restrict__ ve,
                                                       const float* __restrict__ cosb,
                                                       const float* __restrict__ sinb,
                                                       const float* __restrict__ Wgate)
{
    const int wave = (blockIdx.x * blockDim.x + threadIdx.x) >> 6;
    const int lane = threadIdx.x & 63;
    const int NSLOT = Hz + 2 * HKVz;            // 24
    const int hh = wave % NSLOT;
    const int bt = wave / NSLOT;
    if (bt >= ROWS) return;
    const int t = bt % Tz;
    unsigned short* row = qkv + (size_t)bt * QKV_N;

    if (hh < Hz + HKVz) {
        unsigned short* p = (hh < Hz) ? (row + hh * Dz)
                                      : (row + Hz * Dz + (hh - Hz) * Dz);
        float v0 = bf2f(p[lane]);
        float vo = bf2f(p[lane ^ 32]);
        const int dh = lane & 31;
        const float c = cosb[t * 32 + dh];
        const float s = sinb[t * 32 + dh];
        float r = (lane < 32) ? (v0 * c + vo * s) : (v0 * c - vo * s);
        float sq = r * r;
        #pragma unroll
        for (int m = 1; m < 64; m <<= 1) sq += __shfl_xor(sq, m);
        const float scale = rsqrtf(sq * (1.0f / 64.0f) + 1e-6f);
        p[lane] = f2bf(r * scale);
    } else {
        const int hk = hh - (Hz + HKVz);
        float g = (lane < GATE_CHz)
                    ? x[(size_t)bt * Cz + lane] * Wgate[hk * GATE_CHz + lane]
                    : 0.0f;
        #pragma unroll
        for (int m = 1; m < 64; m <<= 1) g += __shfl_xor(g, m);
        const float gate = 2.0f / (1.0f + __expf(-g));
        unsigned short* p = row + Hz * Dz + HKVz * Dz + hk * Dz;
        p[lane] = f2bf(bf2f(p[lane]) + gate * ve[(size_t)bt * (HKVz * Dz) + hk * Dz + lane]);
    }
}

// ---------------------------------------------------------------------------
// MFMA flash attention. Block=(b, hk, 32-query tile), 4 waves = 4 GQA q-heads
// sharing staged K/V. KB=64 chunk. Fixed-max softmax (|q.k|/8 <= 8).
// ---------------------------------------------------------------------------
__global__ __launch_bounds__(256) void attn_mfma(const unsigned short* __restrict__ qkv,
                                                 unsigned short* __restrict__ ybuf,
                                                 const int* __restrict__ winp)
{
    __shared__ unsigned short Ksw[64 * 64];     // [key][d] swizzled, 8KB
    __shared__ unsigned short Vtsw[64 * 64];    // [d][key] swizzled, 8KB
    __shared__ unsigned short Psw[4 * 32 * 64]; // per-wave [q][key] swizzled, 16KB
    __shared__ float lbuf[4][32];

    const int win = winp[0];
    const int tid = threadIdx.x;
    const int wid = tid >> 6, l = tid & 63;
    const int lg = l >> 4, lr = l & 15;
    const int swz = (lr & 7) << 4;

    const int qt = blockIdx.x & 63;             // T/32 = 64 tiles
    const int hk = (blockIdx.x >> 6) & 3;
    const int b  = blockIdx.x >> 8;
    const int h  = hk * 4 + wid;                // this wave's q-head

    const unsigned short* qbase = qkv + (size_t)b * Tz * QKV_N;
    const unsigned short* kvk = qbase + Hz * Dz + hk * Dz;             // +1024+hk*64
    const unsigned short* kvv = qbase + Hz * Dz + HKVz * Dz + hk * Dz; // +1280+hk*64

    // Q fragments (row=query, k=d): lane holds 8 contiguous d at lg*8
    bf16x8 aq[2][2];
    #pragma unroll
    for (int m = 0; m < 2; ++m)
        #pragma unroll
        for (int kk = 0; kk < 2; ++kk)
            aq[m][kk] = *(const bf16x8*)&qbase[(size_t)(qt * 32 + m * 16 + lr) * QKV_N
                                              + h * Dz + kk * 32 + lg * 8];

    f32x4 o[2][4], lac[2];
    #pragma unroll
    for (int m = 0; m < 2; ++m) {
        lac[m] = (f32x4){0.f, 0.f, 0.f, 0.f};
        #pragma unroll
        for (int n = 0; n < 4; ++n) o[m][n] = (f32x4){0.f, 0.f, 0.f, 0.f};
    }
    const unsigned short ov = (lr == 0) ? 0x3F80 : 0;
    const bf16x8 ones = {(short)ov,(short)ov,(short)ov,(short)ov,(short)ov,(short)ov,(short)ov,(short)ov};

    int j0 = qt * 32 - win;
    if (j0 < 0) j0 = 0;
    j0 &= ~63;
    const int jend = qt * 32 + 32;

    char* kb = (char*)Ksw;
    char* vb = (char*)Vtsw;
    char* pb = (char*)Psw + wid * 4096;

    for (int jc = j0; jc < jend; jc += 64) {
        // ---- stage K [key][d]: thread: key=tid>>2, d-block=(tid&3)*16 ----
        {
            const int key = tid >> 2, dq = (tid & 3) * 16;
            const unsigned short* g = &kvk[(size_t)(jc + key) * QKV_N + dq];
            uint4 k0 = *(const uint4*)g;
            uint4 k1 = *(const uint4*)(g + 8);
            const int base = key * 128 + dq * 2;
            const int s2 = (key & 7) << 4;
            *(uint4*)(kb + ((base) ^ s2)) = k0;
            *(uint4*)(kb + ((base + 16) ^ s2)) = k1;
        }
        // ---- stage V transposed Vt[d][key]: thread: key=tid&63, d-block=tid>>6 ----
        {
            const int key = tid & 63, db = tid >> 6;
            const unsigned short* g = &kvv[(size_t)(jc + key) * QKV_N + db * 16];
            union { unsigned short u[16]; uint4 v[2]; } vv;
            vv.v[0] = *(const uint4*)g;
            vv.v[1] = *(const uint4*)(g + 8);
            #pragma unroll
            for (int i2 = 0; i2 < 16; ++i2) {
                const int d = db * 16 + i2;
                *(unsigned short*)(vb + ((d * 128 + key * 2) ^ ((i2 & 7) << 4))) = vv.u[i2];
            }
        }
        __syncthreads();

        // ---- S = Q*K^T ----
        f32x4 s[2][4];
        #pragma unroll
        for (int m = 0; m < 2; ++m)
            #pragma unroll
            for (int n = 0; n < 4; ++n) s[m][n] = (f32x4){0.f, 0.f, 0.f, 0.f};
        #pragma unroll
        for (int kk = 0; kk < 2; ++kk) {
            bf16x8 bk[4];
            #pragma unroll
            for (int n = 0; n < 4; ++n)
                bk[n] = *(const bf16x8*)(kb + (((n * 16 + lr) * 128 + kk * 64 + lg * 16) ^ swz));
            #pragma unroll
            for (int m = 0; m < 2; ++m)
                #pragma unroll
                for (int n = 0; n < 4; ++n)
                    s[m][n] = MFMA16(aq[m][kk], bk[n], s[m][n]);
        }

        // ---- mask + exp(s/8 - 8) -> P (bf16, swizzled per-wave LDS) ----
        #pragma unroll
        for (int m = 0; m < 2; ++m)
            #pragma unroll
            for (int n = 0; n < 4; ++n)
                #pragma unroll
                for (int r = 0; r < 4; ++r) {
                    const int qrow = m * 16 + lg * 4 + r;
                    const int ig = qt * 32 + qrow;
                    const int jg = jc + n * 16 + lr;
                    float p = 0.0f;
                    if (jg <= ig && jg >= ig - win)
                        p = __expf(s[m][n][r] * 0.125f - 8.0f);
                    *(unsigned short*)(pb + ((qrow * 128 + (n * 16 + lr) * 2) ^ ((qrow & 7) << 4)))
                        = f2bf(p);
                }

        // ---- O += P*V ; l += P*ones ----
        #pragma unroll
        for (int kk = 0; kk < 2; ++kk) {
            bf16x8 ap[2], bv[4];
            #pragma unroll
            for (int m = 0; m < 2; ++m)
                ap[m] = *(const bf16x8*)(pb + (((m * 16 + lr) * 128 + kk * 64 + lg * 16) ^ swz));
            #pragma unroll
            for (int n = 0; n < 4; ++n)
                bv[n] = *(const bf16x8*)(vb + (((n * 16 + lr) * 128 + kk * 64 + lg * 16) ^ swz));
            #pragma unroll
            for (int m = 0; m < 2; ++m) {
                lac[m] = MFMA16(ap[m], ones, lac[m]);
                #pragma unroll
                for (int n = 0; n < 4; ++n)
                    o[m][n] = MFMA16(ap[m], bv[n], o[m][n]);
            }
        }
        __syncthreads();
    }

    // ---- normalize + write bf16 ----
    if (lr == 0) {
        #pragma unroll
        for (int m = 0; m < 2; ++m)
            #pragma unroll
            for (int r = 0; r < 4; ++r)
                lbuf[wid][m * 16 + lg * 4 + r] = lac[m][r];
    }
    __syncthreads();

    #pragma unroll
    for (int m = 0; m < 2; ++m)
        #pragma unroll
        for (int r = 0; r < 4; ++r) {
            const int qrow = m * 16 + lg * 4 + r;
            const float inv = 1.0f / lbuf[wid][qrow];
            #pragma unroll
            for (int n = 0; n < 4; ++n)
                ybuf[(size_t)(b * Tz + qt * 32 + qrow) * Cz + h * Dz + n * 16 + lr]
                    = f2bf(o[m][n][r] * inv);
        }
}

// ---------------------------------------------------------------------------
extern "C" void kernel_launch(void* const* d_in, const int* in_sizes, int n_in,
                              void* d_out, int out_size, void* d_ws, size_t ws_size,
                              hipStream_t stream) {
    const float* x     = (const float*)d_in[0];
    const float* ve    = (const float*)d_in[1];
    const float* cosb  = (const float*)d_in[2];
    const float* sinb  = (const float*)d_in[3];
    const float* Wq    = (const float*)d_in[4];
    const float* Wk    = (const float*)d_in[5];
    const float* Wv    = (const float*)d_in[6];
    const float* Wproj = (const float*)d_in[7];
    const float* Wgate = (const float*)d_in[8];
    const int*   winp  = (const int*)d_in[9];
    float* out = (float*)d_out;

    char* w = (char*)d_ws;
    unsigned short* xb    = (unsigned short*)w;  w += (size_t)ROWS * Cz * 2;      // 8 MB
    unsigned short* Wqkvb = (unsigned short*)w;  w += (size_t)QKV_N * Cz * 2;     // 3 MB
    unsigned short* Wpb   = (unsigned short*)w;  w += (size_t)Cz * Cz * 2;        // 2 MB
    unsigned short* qkvb  = (unsigned short*)w;  w += (size_t)ROWS * QKV_N * 2;   // 12 MB
    unsigned short* ybb   = (unsigned short*)w;  w += (size_t)ROWS * Cz * 2;      // 8 MB

    dim3 blk(256);
    auto cvt = [&](const float* s, unsigned short* d, int n) {
        cvt_bf16<<<(n / 8 + 255) / 256, blk, 0, stream>>>(s, d, n);
    };
    cvt(x, xb, ROWS * Cz);
    cvt(Wq, Wqkvb, Hz * Dz * Cz);
    cvt(Wk, Wqkvb + (size_t)(Hz * Dz) * Cz, HKVz * Dz * Cz);
    cvt(Wv, Wqkvb + (size_t)(Hz * Dz + HKVz * Dz) * Cz, HKVz * Dz * Cz);
    cvt(Wproj, Wpb, Cz * Cz);

    // fused QKV projection: [4096 x 1024] x [1536 x 1024]^T -> bf16 qkv
    gemm_bf16<1><<<(QKV_N / 128) * (ROWS / 64), blk, 0, stream>>>(xb, Wqkvb, qkvb, Cz, QKV_N, QKV_N / 128);

    // rope + rmsnorm + gated-v, in place on bf16
    const int n_waves = ROWS * (Hz + 2 * HKVz);
    epilogue_kernel<<<(n_waves * 64) / 256, blk, 0, stream>>>(qkvb, x, ve, cosb, sinb, Wgate);

    // MFMA flash attention -> bf16 ybuf
    attn_mfma<<<Bz * HKVz * (Tz / 32), blk, 0, stream>>>(qkvb, ybb, winp);

    // output projection: [4096 x 1024] x [1024 x 1024]^T -> fp32 out
    gemm_bf16<0><<<(Cz / 128) * (ROWS / 64), blk, 0, stream>>>(ybb, Wpb, out, Cz, Cz, Cz / 128);
}

// Round 8
// 190.484 us; speedup vs baseline: 1.5730x; 1.5730x over previous
//
#include <hip/hip_runtime.h>
#include <hip/hip_bf16.h>
#include <math.h>

#define Bz 2
#define Tz 2048
#define Cz 1024
#define Hz 16
#define HKVz 4
#define Dz 64
#define GATE_CHz 32
#define QKV_N 1536          // H*D + 2*HKV*D
#define ROWS (Bz*Tz)        // 4096

typedef __attribute__((ext_vector_type(8))) short bf16x8;
typedef __attribute__((ext_vector_type(4))) float f32x4;

static __device__ __forceinline__ f32x4 MFMA16(bf16x8 a, bf16x8 b, f32x4 c) {
    return __builtin_amdgcn_mfma_f32_16x16x32_bf16(a, b, c, 0, 0, 0);
}
static __device__ __forceinline__ unsigned short f2bf(float f) {
    unsigned int u = __float_as_uint(f);
    unsigned int r = (u + 0x7FFFu + ((u >> 16) & 1u)) >> 16;   // RNE
    return (unsigned short)r;
}
static __device__ __forceinline__ float bf2f(unsigned short u) {
    return __uint_as_float(((unsigned int)u) << 16);
}

#define AS_GLOBAL(p) ((const __attribute__((address_space(1))) void*)(p))
#define AS_LOCAL(p)  ((__attribute__((address_space(3))) void*)(p))

// ---------------------------------------------------------------------------
// fp32 -> bf16 conversion (8 elems/thread), n % 8 == 0
// ---------------------------------------------------------------------------
__global__ __launch_bounds__(256) void cvt_bf16(const float* __restrict__ s,
                                                unsigned short* __restrict__ d, int n)
{
    int i = (blockIdx.x * 256 + threadIdx.x) * 8;
    if (i >= n) return;
    float4 a = *(const float4*)(s + i);
    float4 b = *(const float4*)(s + i + 4);
    union { unsigned short u[8]; uint4 v; } o;
    o.u[0] = f2bf(a.x); o.u[1] = f2bf(a.y); o.u[2] = f2bf(a.z); o.u[3] = f2bf(a.w);
    o.u[4] = f2bf(b.x); o.u[5] = f2bf(b.y); o.u[6] = f2bf(b.z); o.u[7] = f2bf(b.w);
    *(uint4*)(d + i) = o.v;
}

// ---------------------------------------------------------------------------
// bf16 MFMA GEMM (NT): C[m][n] = sum_k A[m][k]*B[n][k].
// Tile 64(M) x 128(N), BK=64. 4 waves (2x2: 32M x 64N each).
// global_load_lds direct-to-LDS staging (no VGPR roundtrip), double-buffered
// (2 x 24KB), one barrier per K-step. Swizzle: linear LDS dest + pre-swizzled
// global source chunk (c ^= row&7 within 128B row) + same XOR on reads.
// LDS-staged coalesced C-write. OB=1: bf16 out, OB=0: fp32 out.
// M fixed = 4096 (gy=64); gx = N/128; grid = gx*64 (%8==0), XCD-swizzled.
// ---------------------------------------------------------------------------
template<int OB>
__global__ __launch_bounds__(256) void gemm_bf16(const unsigned short* __restrict__ A,
                                                 const unsigned short* __restrict__ Bw,
                                                 void* __restrict__ Cv, int K, int ldc,
                                                 int gx)
{
    // per buffer: A[64][64]bf16 (8KB) at +0, B[128][64]bf16 (16KB) at +4096 shorts
    __shared__ unsigned short smem[2 * 12288];      // 48 KB
    const int tid = threadIdx.x;
    const int wid = tid >> 6, l = tid & 63;
    const int wr = wid >> 1, wc = wid & 1;
    const int lg = l >> 4, lr = l & 15;
    const int swz = (lr & 7) << 4;

    // XCD-aware bijective swizzle (grid % 8 == 0)
    const int nwg = gx * 64;
    const int cpx = nwg >> 3;
    const int sbid = (blockIdx.x & 7) * cpx + (blockIdx.x >> 3);
    const int bx = sbid % gx;
    const int by = sbid / gx;

    // staging lane map: row = r0 + (l>>3), chunk = (l&7) ^ (row&7); row&7 == l>>3
    const int lrow = l >> 3, lch = l & 7;
    const int schunk = (lch ^ lrow) << 4;           // pre-swizzled byte offset in row

    const char* Agl = (const char*)(A + (size_t)(by * 64 + lrow) * K) + schunk;
    const char* Bgl = (const char*)(Bw + (size_t)(bx * 128 + lrow) * K) + schunk;
    const size_t rowK = (size_t)K * 2;              // bytes per global row

    f32x4 acc[2][4];
    #pragma unroll
    for (int m = 0; m < 2; ++m)
        #pragma unroll
        for (int n = 0; n < 4; ++n)
            acc[m][n] = (f32x4){0.f, 0.f, 0.f, 0.f};

    const int nk = K / 64;

    // ---- stage K-tile ki into buffer buf (6 global_load_lds per thread) ----
    auto stage = [&](int buf, int ki) {
        unsigned short* base = smem + buf * 12288;
        const size_t kb = (size_t)ki * 128;         // byte offset into K row
        #pragma unroll
        for (int j = 0; j < 2; ++j) {
            const int r0 = j * 32 + wid * 8;
            __builtin_amdgcn_global_load_lds(AS_GLOBAL(Agl + (size_t)r0 * rowK + kb),
                                             AS_LOCAL(base + r0 * 64), 16, 0, 0);
        }
        #pragma unroll
        for (int j = 0; j < 4; ++j) {
            const int r0 = j * 32 + wid * 8;
            __builtin_amdgcn_global_load_lds(AS_GLOBAL(Bgl + (size_t)r0 * rowK + kb),
                                             AS_LOCAL(base + 4096 + r0 * 64), 16, 0, 0);
        }
    };

    stage(0, 0);
    __syncthreads();                                 // drains vmcnt+barrier

    for (int ki = 0; ki < nk; ++ki) {
        const int cur = ki & 1;
        if (ki + 1 < nk) stage(cur ^ 1, ki + 1);     // DMA next tile during compute

        char* ab = (char*)(smem + cur * 12288);
        char* bb = ab + 8192;
        #pragma unroll
        for (int kk = 0; kk < 2; ++kk) {
            bf16x8 av[2], bv[4];
            #pragma unroll
            for (int m = 0; m < 2; ++m)
                av[m] = *(const bf16x8*)(ab + (((wr * 32 + m * 16 + lr) * 128 + kk * 64 + lg * 16) ^ swz));
            #pragma unroll
            for (int n = 0; n < 4; ++n)
                bv[n] = *(const bf16x8*)(bb + (((wc * 64 + n * 16 + lr) * 128 + kk * 64 + lg * 16) ^ swz));
            #pragma unroll
            for (int m = 0; m < 2; ++m)
                #pragma unroll
                for (int n = 0; n < 4; ++n)
                    acc[m][n] = MFMA16(av[m], bv[n], acc[m][n]);
        }
        __syncthreads();                             // drains DMA (vmcnt0) + read fence
    }

    // ---- LDS-staged coalesced C-write ----
    if (OB) {
        unsigned short* cs = smem;                   // 16KB tile
        #pragma unroll
        for (int m = 0; m < 2; ++m)
            #pragma unroll
            for (int n = 0; n < 4; ++n)
                #pragma unroll
                for (int r = 0; r < 4; ++r)
                    cs[(wr * 32 + m * 16 + lg * 4 + r) * 128 + wc * 64 + n * 16 + lr]
                        = f2bf(acc[m][n][r]);
        __syncthreads();
        unsigned short* C = (unsigned short*)Cv;
        #pragma unroll
        for (int it = 0; it < 4; ++it) {
            const int idx = it * 256 + tid;
            const int row = idx >> 4, c16 = idx & 15;
            *(uint4*)&C[(size_t)(by * 64 + row) * ldc + bx * 128 + c16 * 8]
                = *(const uint4*)&cs[row * 128 + c16 * 8];
        }
    } else {
        float* cf = (float*)smem;                    // 16KB half-tile
        float* C = (float*)Cv;
        #pragma unroll
        for (int p = 0; p < 2; ++p) {
            if (wr == p) {
                #pragma unroll
                for (int m = 0; m < 2; ++m)
                    #pragma unroll
                    for (int n = 0; n < 4; ++n)
                        #pragma unroll
                        for (int r = 0; r < 4; ++r)
                            cf[(m * 16 + lg * 4 + r) * 128 + wc * 64 + n * 16 + lr]
                                = acc[m][n][r];
            }
            __syncthreads();
            #pragma unroll
            for (int it = 0; it < 4; ++it) {
                const int idx = it * 256 + tid;
                const int row = idx >> 5, c32 = idx & 31;
                *(uint4*)&C[(size_t)(by * 64 + p * 32 + row) * ldc + bx * 128 + c32 * 4]
                    = *(const uint4*)&cf[row * 128 + c32 * 4];
            }
            __syncthreads();
        }
    }
}

// ---------------------------------------------------------------------------
// Epilogue on bf16 qkv: one wave per (row, head-slot).
// slots 0..15 q, 16..19 k (rope+rms); 20..23 v (gate*ve add).
// ---------------------------------------------------------------------------
__global__ __launch_bounds__(256) void epilogue_kernel(unsigned short* __restrict__ qkv,
                                                       const float* __restrict__ x,
                                                       const float* __restrict__ ve,
                                                       const float* __restrict__ cosb,
                                                       const float* __restrict__ sinb,
                                                       const float* __restrict__ Wgate)
{
    const int wave = (blockIdx.x * blockDim.x + threadIdx.x) >> 6;
    const int lane = threadIdx.x & 63;
    const int NSLOT = Hz + 2 * HKVz;            // 24
    const int hh = wave % NSLOT;
    const int bt = wave / NSLOT;
    if (bt >= ROWS) return;
    const int t = bt % Tz;
    unsigned short* row = qkv + (size_t)bt * QKV_N;

    if (hh < Hz + HKVz) {
        unsigned short* p = (hh < Hz) ? (row + hh * Dz)
                                      : (row + Hz * Dz + (hh - Hz) * Dz);
        float v0 = bf2f(p[lane]);
        float vo = bf2f(p[lane ^ 32]);
        const int dh = lane & 31;
        const float c = cosb[t * 32 + dh];
        const float s = sinb[t * 32 + dh];
        float r = (lane < 32) ? (v0 * c + vo * s) : (v0 * c - vo * s);
        float sq = r * r;
        #pragma unroll
        for (int m = 1; m < 64; m <<= 1) sq += __shfl_xor(sq, m);
        const float scale = rsqrtf(sq * (1.0f / 64.0f) + 1e-6f);
        p[lane] = f2bf(r * scale);
    } else {
        const int hk = hh - (Hz + HKVz);
        float g = (lane < GATE_CHz)
                    ? x[(size_t)bt * Cz + lane] * Wgate[hk * GATE_CHz + lane]
                    : 0.0f;
        #pragma unroll
        for (int m = 1; m < 64; m <<= 1) g += __shfl_xor(g, m);
        const float gate = 2.0f / (1.0f + __expf(-g));
        unsigned short* p = row + Hz * Dz + HKVz * Dz + hk * Dz;
        p[lane] = f2bf(bf2f(p[lane]) + gate * ve[(size_t)bt * (HKVz * Dz) + hk * Dz + lane]);
    }
}

// ---------------------------------------------------------------------------
// MFMA flash attention. Block=(b, hk, 32-query tile), 4 waves = 4 GQA q-heads
// sharing staged K/V. KB=64 chunk. Fixed-max softmax (|q.k|/8 <= 8).
// ---------------------------------------------------------------------------
__global__ __launch_bounds__(256) void attn_mfma(const unsigned short* __restrict__ qkv,
                                                 unsigned short* __restrict__ ybuf,
                                                 const int* __restrict__ winp)
{
    __shared__ unsigned short Ksw[64 * 64];     // [key][d] swizzled, 8KB
    __shared__ unsigned short Vtsw[64 * 64];    // [d][key] swizzled, 8KB
    __shared__ unsigned short Psw[4 * 32 * 64]; // per-wave [q][key] swizzled, 16KB
    __shared__ float lbuf[4][32];

    const int win = winp[0];
    const int tid = threadIdx.x;
    const int wid = tid >> 6, l = tid & 63;
    const int lg = l >> 4, lr = l & 15;
    const int swz = (lr & 7) << 4;

    const int qt = blockIdx.x & 63;             // T/32 = 64 tiles
    const int hk = (blockIdx.x >> 6) & 3;
    const int b  = blockIdx.x >> 8;
    const int h  = hk * 4 + wid;                // this wave's q-head

    const unsigned short* qbase = qkv + (size_t)b * Tz * QKV_N;
    const unsigned short* kvk = qbase + Hz * Dz + hk * Dz;             // +1024+hk*64
    const unsigned short* kvv = qbase + Hz * Dz + HKVz * Dz + hk * Dz; // +1280+hk*64

    // Q fragments (row=query, k=d): lane holds 8 contiguous d at lg*8
    bf16x8 aq[2][2];
    #pragma unroll
    for (int m = 0; m < 2; ++m)
        #pragma unroll
        for (int kk = 0; kk < 2; ++kk)
            aq[m][kk] = *(const bf16x8*)&qbase[(size_t)(qt * 32 + m * 16 + lr) * QKV_N
                                              + h * Dz + kk * 32 + lg * 8];

    f32x4 o[2][4], lac[2];
    #pragma unroll
    for (int m = 0; m < 2; ++m) {
        lac[m] = (f32x4){0.f, 0.f, 0.f, 0.f};
        #pragma unroll
        for (int n = 0; n < 4; ++n) o[m][n] = (f32x4){0.f, 0.f, 0.f, 0.f};
    }
    const unsigned short ov = (lr == 0) ? 0x3F80 : 0;
    const bf16x8 ones = {(short)ov,(short)ov,(short)ov,(short)ov,(short)ov,(short)ov,(short)ov,(short)ov};

    int j0 = qt * 32 - win;
    if (j0 < 0) j0 = 0;
    j0 &= ~63;
    const int jend = qt * 32 + 32;

    char* kb = (char*)Ksw;
    char* vb = (char*)Vtsw;
    char* pb = (char*)Psw + wid * 4096;

    for (int jc = j0; jc < jend; jc += 64) {
        // ---- stage K [key][d]: thread: key=tid>>2, d-block=(tid&3)*16 ----
        {
            const int key = tid >> 2, dq = (tid & 3) * 16;
            const unsigned short* g = &kvk[(size_t)(jc + key) * QKV_N + dq];
            uint4 k0 = *(const uint4*)g;
            uint4 k1 = *(const uint4*)(g + 8);
            const int base = key * 128 + dq * 2;
            const int s2 = (key & 7) << 4;
            *(uint4*)(kb + ((base) ^ s2)) = k0;
            *(uint4*)(kb + ((base + 16) ^ s2)) = k1;
        }
        // ---- stage V transposed Vt[d][key]: thread: key=tid&63, d-block=tid>>6 ----
        {
            const int key = tid & 63, db = tid >> 6;
            const unsigned short* g = &kvv[(size_t)(jc + key) * QKV_N + db * 16];
            union { unsigned short u[16]; uint4 v[2]; } vv;
            vv.v[0] = *(const uint4*)g;
            vv.v[1] = *(const uint4*)(g + 8);
            #pragma unroll
            for (int i2 = 0; i2 < 16; ++i2) {
                const int d = db * 16 + i2;
                *(unsigned short*)(vb + ((d * 128 + key * 2) ^ ((i2 & 7) << 4))) = vv.u[i2];
            }
        }
        __syncthreads();

        // ---- S = Q*K^T ----
        f32x4 s[2][4];
        #pragma unroll
        for (int m = 0; m < 2; ++m)
            #pragma unroll
            for (int n = 0; n < 4; ++n) s[m][n] = (f32x4){0.f, 0.f, 0.f, 0.f};
        #pragma unroll
        for (int kk = 0; kk < 2; ++kk) {
            bf16x8 bk[4];
            #pragma unroll
            for (int n = 0; n < 4; ++n)
                bk[n] = *(const bf16x8*)(kb + (((n * 16 + lr) * 128 + kk * 64 + lg * 16) ^ swz));
            #pragma unroll
            for (int m = 0; m < 2; ++m)
                #pragma unroll
                for (int n = 0; n < 4; ++n)
                    s[m][n] = MFMA16(aq[m][kk], bk[n], s[m][n]);
        }

        // ---- mask + exp(s/8 - 8) -> P (bf16, swizzled per-wave LDS) ----
        #pragma unroll
        for (int m = 0; m < 2; ++m)
            #pragma unroll
            for (int n = 0; n < 4; ++n)
                #pragma unroll
                for (int r = 0; r < 4; ++r) {
                    const int qrow = m * 16 + lg * 4 + r;
                    const int ig = qt * 32 + qrow;
                    const int jg = jc + n * 16 + lr;
                    float p = 0.0f;
                    if (jg <= ig && jg >= ig - win)
                        p = __expf(s[m][n][r] * 0.125f - 8.0f);
                    *(unsigned short*)(pb + ((qrow * 128 + (n * 16 + lr) * 2) ^ ((qrow & 7) << 4)))
                        = f2bf(p);
                }

        // ---- O += P*V ; l += P*ones ----
        #pragma unroll
        for (int kk = 0; kk < 2; ++kk) {
            bf16x8 ap[2], bv[4];
            #pragma unroll
            for (int m = 0; m < 2; ++m)
                ap[m] = *(const bf16x8*)(pb + (((m * 16 + lr) * 128 + kk * 64 + lg * 16) ^ swz));
            #pragma unroll
            for (int n = 0; n < 4; ++n)
                bv[n] = *(const bf16x8*)(vb + (((n * 16 + lr) * 128 + kk * 64 + lg * 16) ^ swz));
            #pragma unroll
            for (int m = 0; m < 2; ++m) {
                lac[m] = MFMA16(ap[m], ones, lac[m]);
                #pragma unroll
                for (int n = 0; n < 4; ++n)
                    o[m][n] = MFMA16(ap[m], bv[n], o[m][n]);
            }
        }
        __syncthreads();
    }

    // ---- normalize + write bf16 ----
    if (lr == 0) {
        #pragma unroll
        for (int m = 0; m < 2; ++m)
            #pragma unroll
            for (int r = 0; r < 4; ++r)
                lbuf[wid][m * 16 + lg * 4 + r] = lac[m][r];
    }
    __syncthreads();

    #pragma unroll
    for (int m = 0; m < 2; ++m)
        #pragma unroll
        for (int r = 0; r < 4; ++r) {
            const int qrow = m * 16 + lg * 4 + r;
            const float inv = 1.0f / lbuf[wid][qrow];
            #pragma unroll
            for (int n = 0; n < 4; ++n)
                ybuf[(size_t)(b * Tz + qt * 32 + qrow) * Cz + h * Dz + n * 16 + lr]
                    = f2bf(o[m][n][r] * inv);
        }
}

// ---------------------------------------------------------------------------
extern "C" void kernel_launch(void* const* d_in, const int* in_sizes, int n_in,
                              void* d_out, int out_size, void* d_ws, size_t ws_size,
                              hipStream_t stream) {
    const float* x     = (const float*)d_in[0];
    const float* ve    = (const float*)d_in[1];
    const float* cosb  = (const float*)d_in[2];
    const float* sinb  = (const float*)d_in[3];
    const float* Wq    = (const float*)d_in[4];
    const float* Wk    = (const float*)d_in[5];
    const float* Wv    = (const float*)d_in[6];
    const float* Wproj = (const float*)d_in[7];
    const float* Wgate = (const float*)d_in[8];
    const int*   winp  = (const int*)d_in[9];
    float* out = (float*)d_out;

    char* w = (char*)d_ws;
    unsigned short* xb    = (unsigned short*)w;  w += (size_t)ROWS * Cz * 2;      // 8 MB
    unsigned short* Wqkvb = (unsigned short*)w;  w += (size_t)QKV_N * Cz * 2;     // 3 MB
    unsigned short* Wpb   = (unsigned short*)w;  w += (size_t)Cz * Cz * 2;        // 2 MB
    unsigned short* qkvb  = (unsigned short*)w;  w += (size_t)ROWS * QKV_N * 2;   // 12 MB
    unsigned short* ybb   = (unsigned short*)w;  w += (size_t)ROWS * Cz * 2;      // 8 MB

    dim3 blk(256);
    auto cvt = [&](const float* s, unsigned short* d, int n) {
        cvt_bf16<<<(n / 8 + 255) / 256, blk, 0, stream>>>(s, d, n);
    };
    cvt(x, xb, ROWS * Cz);
    cvt(Wq, Wqkvb, Hz * Dz * Cz);
    cvt(Wk, Wqkvb + (size_t)(Hz * Dz) * Cz, HKVz * Dz * Cz);
    cvt(Wv, Wqkvb + (size_t)(Hz * Dz + HKVz * Dz) * Cz, HKVz * Dz * Cz);
    cvt(Wproj, Wpb, Cz * Cz);

    // fused QKV projection: [4096 x 1024] x [1536 x 1024]^T -> bf16 qkv
    gemm_bf16<1><<<(QKV_N / 128) * (ROWS / 64), blk, 0, stream>>>(xb, Wqkvb, qkvb, Cz, QKV_N, QKV_N / 128);

    // rope + rmsnorm + gated-v, in place on bf16
    const int n_waves = ROWS * (Hz + 2 * HKVz);
    epilogue_kernel<<<(n_waves * 64) / 256, blk, 0, stream>>>(qkvb, x, ve, cosb, sinb, Wgate);

    // MFMA flash attention -> bf16 ybuf
    attn_mfma<<<Bz * HKVz * (Tz / 32), blk, 0, stream>>>(qkvb, ybb, winp);

    // output projection: [4096 x 1024] x [1024 x 1024]^T -> fp32 out
    gemm_bf16<0><<<(Cz / 128) * (ROWS / 64), blk, 0, stream>>>(ybb, Wpb, out, Cz, Cz, Cz / 128);
}